// Round 3
// baseline (587.286 us; speedup 1.0000x reference)
//
#include <hip/hip_runtime.h>
#include <hip/hip_bf16.h>

#define B_ 4096
#define K_ 64
#define N_ 100000
#define E_ 128
#define T_ 3

typedef __bf16 bf16x8 __attribute__((ext_vector_type(8)));
typedef float  f32x4  __attribute__((ext_vector_type(4)));

static __device__ __forceinline__ bf16x8 cvt8(const float* s) {
    const float4 u = *(const float4*)s;
    const float4 v = *(const float4*)(s + 4);
    bf16x8 o;
    o[0] = (__bf16)u.x; o[1] = (__bf16)u.y; o[2] = (__bf16)u.z; o[3] = (__bf16)u.w;
    o[4] = (__bf16)v.x; o[5] = (__bf16)v.y; o[6] = (__bf16)v.z; o[7] = (__bf16)v.w;
    return o;
}

// ---------------------------------------------------------------------------
// Kernel 0: transpose + bf16-convert weight matrices.
//   WtF [128][256] <- W_f[256][128];  Wa1t/Wa2t/W1t [128][128] <- top/orig
// ---------------------------------------------------------------------------
__global__ __launch_bounds__(256)
void k_prep(const float* __restrict__ W_f, const float* __restrict__ Wa1,
            const float* __restrict__ Wa2, const float* __restrict__ W1,
            __bf16* __restrict__ WtF, __bf16* __restrict__ Wa1t,
            __bf16* __restrict__ Wa2t, __bf16* __restrict__ W1t) {
    const int n = blockIdx.x;      // output row = original col
    const int k = threadIdx.x;
    if (blockIdx.y == 0) {
        WtF[n * 256 + k] = (__bf16)W_f[k * 128 + n];
    } else if (blockIdx.y == 1) {
        if (k < 128) Wa1t[n * 128 + k] = (__bf16)Wa1[k * 128 + n];
    } else if (blockIdx.y == 2) {
        if (k < 128) Wa2t[n * 128 + k] = (__bf16)Wa2[k * 128 + n];
    } else {
        if (k < 128) W1t[n * 128 + k] = (__bf16)W1[k * 128 + n];
    }
}

// ---------------------------------------------------------------------------
// Kernel 1: nodes_fusion[b] = relu(concat(node_emb[nd], node_prof[nd]) @ W_f + b_f)
// (bf16 output)
// ---------------------------------------------------------------------------
__global__ __launch_bounds__(128)
void k_node_fusion(const int* __restrict__ nodes,
                   const float* __restrict__ node_emb,
                   const float* __restrict__ node_prof,
                   const float* __restrict__ W_f, const float* __restrict__ b_f,
                   __bf16* __restrict__ nodes_fusion) {
    __shared__ float x[256];
    const int b = blockIdx.x;
    const int e = threadIdx.x;          // 0..127
    const int nd = nodes[b];
    x[e]       = node_emb[(size_t)nd * E_ + e];
    x[128 + e] = node_prof[(size_t)nd * E_ + e];
    __syncthreads();
    float acc = b_f[e];
#pragma unroll 8
    for (int i = 0; i < 256; ++i) acc = fmaf(x[i], W_f[i * E_ + e], acc);
    nodes_fusion[(size_t)b * E_ + e] = (__bf16)fmaxf(acc, 0.f);
}

// ---------------------------------------------------------------------------
// Kernel 1b: node_pre[b][c] = ba1[c] + nodes_fusion[b] . Wa1[128+..][c]  (bf16 out)
// ---------------------------------------------------------------------------
__global__ __launch_bounds__(128)
void k_node_pre(const __bf16* __restrict__ nodes_fusion,
                const float* __restrict__ Wa1, const float* __restrict__ ba1,
                __bf16* __restrict__ node_pre) {
    __shared__ float x[128];
    const int b = blockIdx.x;
    const int c = threadIdx.x;
    x[c] = (float)nodes_fusion[(size_t)b * E_ + c];
    __syncthreads();
    float acc = ba1[c];
#pragma unroll 8
    for (int i = 0; i < 128; ++i) acc = fmaf(x[i], Wa1[(128 + i) * E_ + c], acc);
    node_pre[(size_t)b * E_ + c] = (__bf16)acc;
}

// ---------------------------------------------------------------------------
// Kernel 2 (hot): per (b,t) block, 4 waves of 64.
// Wave w owns rows [32*(w>>1), +32) x cols [64*(w&1), +64)  (2 M-tiles x 4 N-tiles).
// GEMM1 A-operand gathered DIRECTLY from global into MFMA fragments (no X LDS).
// NF / H1 staged in LDS only for the GEMM2/GEMM3 transposes + final agg.
// Barriers: after NF, after H1, after scores, after softmax  (4 total).
// ---------------------------------------------------------------------------
__global__ __launch_bounds__(256, 4)
void k_neigh_att(const int* __restrict__ neigh_idx,
                 const float* __restrict__ neigh_emb,
                 const float* __restrict__ neigh_prof,
                 const __bf16* __restrict__ WtF,
                 const __bf16* __restrict__ Wa1t,
                 const __bf16* __restrict__ Wa2t,
                 const float* __restrict__ b_f,
                 const float* __restrict__ ba2,
                 const float* __restrict__ Wa3, const float* __restrict__ ba3,
                 const __bf16* __restrict__ node_pre,
                 __bf16* __restrict__ aggB) {
    __shared__ __bf16 NFl[64 * 136];    // 17408 B
    __shared__ __bf16 H1l[64 * 136];    // 17408 B
    __shared__ float  scp[128];         // per-col-half score partials
    __shared__ float  att_s[64];

    const int b    = blockIdx.x;
    const int t    = blockIdx.y;
    const int tid  = threadIdx.x;
    const int wid  = tid >> 6;
    const int lane = tid & 63;
    const int lr   = lane & 15;
    const int lk   = lane >> 4;
    const int mp   = wid >> 1;          // row pair 0/1 -> rows 32*mp..+32
    const int h    = wid & 1;           // col half

    const int r0 = 32 * mp + lr;        // A row, mi=0
    const int r1 = r0 + 16;             // A row, mi=1

    const float* emb_t   = neigh_emb  + (size_t)t * N_ * E_;
    const float* prof_t  = neigh_prof + (size_t)t * N_ * E_;
    const int*   idx_row = neigh_idx  + ((size_t)t * B_ + b) * K_;

    const int id0 = idx_row[r0];
    const int id1 = idx_row[r1];
    const float* e0p = emb_t  + (size_t)id0 * E_ + lk * 8;
    const float* e1p = emb_t  + (size_t)id1 * E_ + lk * 8;
    const float* p0p = prof_t + (size_t)id0 * E_ + lk * 8;
    const float* p1p = prof_t + (size_t)id1 * E_ + lk * 8;

    // ---- GEMM1: NF = relu(X @ W_f + b_f), K=256, A gathered to registers ----
    {
        f32x4 acc[2][4] = {};
#pragma unroll 2
        for (int ks = 0; ks < 8; ++ks) {
            const int o = (ks & 3) * 32;
            const bf16x8 a0 = cvt8((ks < 4 ? e0p : p0p) + o);
            const bf16x8 a1 = cvt8((ks < 4 ? e1p : p1p) + o);
            const __bf16* wb = WtF + (size_t)(h * 64 + lr) * 256 + ks * 32 + lk * 8;
#pragma unroll
            for (int n = 0; n < 4; ++n) {
                const bf16x8 w = *(const bf16x8*)(wb + n * 16 * 256);
                acc[0][n] = __builtin_amdgcn_mfma_f32_16x16x32_bf16(a0, w, acc[0][n], 0, 0, 0);
                acc[1][n] = __builtin_amdgcn_mfma_f32_16x16x32_bf16(a1, w, acc[1][n], 0, 0, 0);
            }
        }
#pragma unroll
        for (int n = 0; n < 4; ++n) {
            const int col = h * 64 + n * 16 + lr;
            const float bb = b_f[col];
#pragma unroll
            for (int j = 0; j < 4; ++j) {
                NFl[(32 * mp + lk * 4 + j) * 136 + col]      = (__bf16)fmaxf(acc[0][n][j] + bb, 0.f);
                NFl[(32 * mp + 16 + lk * 4 + j) * 136 + col] = (__bf16)fmaxf(acc[1][n][j] + bb, 0.f);
            }
        }
    }
    __syncthreads();

    // ---- GEMM2: H1 = relu(NF @ Wa1_top + node_pre), K=128 ----
    {
        f32x4 acc[2][4] = {};
#pragma unroll
        for (int ks = 0; ks < 4; ++ks) {
            const bf16x8 a0 = *(const bf16x8*)&NFl[r0 * 136 + ks * 32 + lk * 8];
            const bf16x8 a1 = *(const bf16x8*)&NFl[r1 * 136 + ks * 32 + lk * 8];
            const __bf16* wb = Wa1t + (size_t)(h * 64 + lr) * 128 + ks * 32 + lk * 8;
#pragma unroll
            for (int n = 0; n < 4; ++n) {
                const bf16x8 w = *(const bf16x8*)(wb + n * 16 * 128);
                acc[0][n] = __builtin_amdgcn_mfma_f32_16x16x32_bf16(a0, w, acc[0][n], 0, 0, 0);
                acc[1][n] = __builtin_amdgcn_mfma_f32_16x16x32_bf16(a1, w, acc[1][n], 0, 0, 0);
            }
        }
#pragma unroll
        for (int n = 0; n < 4; ++n) {
            const int col = h * 64 + n * 16 + lr;
            const float pp = (float)node_pre[(size_t)b * E_ + col];
#pragma unroll
            for (int j = 0; j < 4; ++j) {
                H1l[(32 * mp + lk * 4 + j) * 136 + col]      = (__bf16)fmaxf(acc[0][n][j] + pp, 0.f);
                H1l[(32 * mp + 16 + lk * 4 + j) * 136 + col] = (__bf16)fmaxf(acc[1][n][j] + pp, 0.f);
            }
        }
    }
    __syncthreads();

    // ---- GEMM3 + scores: s = relu(H1 @ Wa2 + ba2) @ Wa3 ----
    {
        f32x4 acc[2][4] = {};
#pragma unroll
        for (int ks = 0; ks < 4; ++ks) {
            const bf16x8 a0 = *(const bf16x8*)&H1l[r0 * 136 + ks * 32 + lk * 8];
            const bf16x8 a1 = *(const bf16x8*)&H1l[r1 * 136 + ks * 32 + lk * 8];
            const __bf16* wb = Wa2t + (size_t)(h * 64 + lr) * 128 + ks * 32 + lk * 8;
#pragma unroll
            for (int n = 0; n < 4; ++n) {
                const bf16x8 w = *(const bf16x8*)(wb + n * 16 * 128);
                acc[0][n] = __builtin_amdgcn_mfma_f32_16x16x32_bf16(a0, w, acc[0][n], 0, 0, 0);
                acc[1][n] = __builtin_amdgcn_mfma_f32_16x16x32_bf16(a1, w, acc[1][n], 0, 0, 0);
            }
        }
        float ba2r[4], wa3r[4];
#pragma unroll
        for (int n = 0; n < 4; ++n) {
            const int col = h * 64 + n * 16 + lr;
            ba2r[n] = ba2[col];
            wa3r[n] = Wa3[col];
        }
#pragma unroll
        for (int mi = 0; mi < 2; ++mi)
#pragma unroll
            for (int j = 0; j < 4; ++j) {
                float v = 0.f;
#pragma unroll
                for (int n = 0; n < 4; ++n)
                    v += fmaxf(acc[mi][n][j] + ba2r[n], 0.f) * wa3r[n];
                v += __shfl_xor(v, 1);
                v += __shfl_xor(v, 2);
                v += __shfl_xor(v, 4);
                v += __shfl_xor(v, 8);
                if (lr == 0)
                    scp[h * 64 + 32 * mp + mi * 16 + lk * 4 + j] = v;
            }
    }
    __syncthreads();

    // ---- softmax over K=64 (wave 0) ----
    if (tid < 64) {
        const float v = scp[tid] + scp[64 + tid] + ba3[0];
        float m = v;
#pragma unroll
        for (int o = 32; o > 0; o >>= 1) m = fmaxf(m, __shfl_xor(m, o));
        const float pe = __expf(v - m);
        float s = pe;
#pragma unroll
        for (int o = 32; o > 0; o >>= 1) s += __shfl_xor(s, o);
        att_s[tid] = pe / s;
    }
    __syncthreads();

    // ---- agg[e] = sum_n att[n] * NF[n][e]  -> bf16 aggB ----
    if (tid < 128) {
        float a = 0.f;
#pragma unroll 8
        for (int n = 0; n < 64; ++n)
            a = fmaf(att_s[n], (float)NFl[n * 136 + tid], a);
        aggB[((size_t)b * T_ + t) * E_ + tid] = (__bf16)a;
    }
}

// ---------------------------------------------------------------------------
// Kernel 2b: type_agg = relu(aggB @ W1 + b1), M=B*T, K=N=128. MFMA, no LDS.
// ---------------------------------------------------------------------------
__global__ __launch_bounds__(256)
void k_w1(const __bf16* __restrict__ aggB, const __bf16* __restrict__ W1t,
          const float* __restrict__ b1, __bf16* __restrict__ type_agg) {
    const int tid  = threadIdx.x;
    const int wid  = tid >> 6;
    const int lane = tid & 63;
    const int lr   = lane & 15;
    const int lk   = lane >> 4;
    const int rbase = blockIdx.x * 64 + wid * 16;

    f32x4 acc[8] = {};
#pragma unroll
    for (int ks = 0; ks < 4; ++ks) {
        const bf16x8 a = *(const bf16x8*)&aggB[(size_t)(rbase + lr) * 128 + ks * 32 + lk * 8];
        const __bf16* wb = W1t + (size_t)lr * 128 + ks * 32 + lk * 8;
#pragma unroll
        for (int n = 0; n < 8; ++n) {
            const bf16x8 w = *(const bf16x8*)(wb + n * 16 * 128);
            acc[n] = __builtin_amdgcn_mfma_f32_16x16x32_bf16(a, w, acc[n], 0, 0, 0);
        }
    }
#pragma unroll
    for (int n = 0; n < 8; ++n) {
        const int col = n * 16 + lr;
        const float bb = b1[col];
#pragma unroll
        for (int j = 0; j < 4; ++j) {
            const int row = rbase + lk * 4 + j;
            type_agg[(size_t)row * 128 + col] = (__bf16)fmaxf(acc[n][j] + bb, 0.f);
        }
    }
}

// ---------------------------------------------------------------------------
// Kernel 3: type softmax + final MLP + output head.
// ---------------------------------------------------------------------------
__global__ __launch_bounds__(128)
void k_final(const __bf16* __restrict__ type_agg,
             const __bf16* __restrict__ nodes_fusion,
             const float* __restrict__ Wt,
             const float* __restrict__ W2, const float* __restrict__ b2,
             const float* __restrict__ Wc, const float* __restrict__ bc,
             float* __restrict__ out, float* __restrict__ att_out) {
    __shared__ float ta[384];
    __shared__ float nfu[128];
    __shared__ float fin[128];
    __shared__ float hb[128];
    __shared__ float att[3];
    __shared__ float red[3][128];

    const int b = blockIdx.x;
    const int e = threadIdx.x;   // 0..127

    const float v0 = (float)type_agg[(size_t)b * 384 + e];
    const float v1 = (float)type_agg[(size_t)b * 384 + 128 + e];
    const float v2 = (float)type_agg[(size_t)b * 384 + 256 + e];
    ta[e] = v0; ta[128 + e] = v1; ta[256 + e] = v2;
    nfu[e] = (float)nodes_fusion[(size_t)b * E_ + e];

    float p0, p1, p2;
    {
        const float* w0 = Wt + (size_t)e * 3;
        const float* w1 = Wt + (size_t)(128 + e) * 3;
        const float* w2 = Wt + (size_t)(256 + e) * 3;
        p0 = v0 * w0[0] + v1 * w1[0] + v2 * w2[0];
        p1 = v0 * w0[1] + v1 * w1[1] + v2 * w2[1];
        p2 = v0 * w0[2] + v1 * w1[2] + v2 * w2[2];
    }
    red[0][e] = p0; red[1][e] = p1; red[2][e] = p2;
    __syncthreads();

    if (e < 3) {
        float s = 0.f;
        for (int i = 0; i < 128; ++i) s += red[e][i];
        red[e][0] = s;
    }
    __syncthreads();
    if (e == 0) {
        const float s0 = red[0][0], s1 = red[1][0], s2 = red[2][0];
        const float m  = fmaxf(s0, fmaxf(s1, s2));
        const float e0 = __expf(s0 - m), e1 = __expf(s1 - m), e2 = __expf(s2 - m);
        const float inv = 1.f / (e0 + e1 + e2);
        att[0] = e0 * inv; att[1] = e1 * inv; att[2] = e2 * inv;
    }
    __syncthreads();

    fin[e] = att[0] * ta[e] + att[1] * ta[128 + e] + att[2] * ta[256 + e];
    __syncthreads();

    float acc = b2[e];
#pragma unroll 8
    for (int i = 0; i < 128; ++i) acc = fmaf(fin[i], W2[i * E_ + e], acc);
    hb[e] = fmaxf(acc, 0.f);
    __syncthreads();

    float acc2 = bc[e];
#pragma unroll 8
    for (int i = 0; i < 128; ++i) acc2 = fmaf(nfu[i], Wc[i * E_ + e], acc2);
#pragma unroll 8
    for (int i = 0; i < 128; ++i) acc2 = fmaf(hb[i], Wc[(128 + i) * E_ + e], acc2);
    out[(size_t)b * E_ + e] = fmaxf(acc2, 0.f);

    if (e < 3) att_out[(size_t)b * 3 + e] = att[e];
}

// ---------------------------------------------------------------------------
extern "C" void kernel_launch(void* const* d_in, const int* in_sizes, int n_in,
                              void* d_out, int out_size, void* d_ws, size_t ws_size,
                              hipStream_t stream) {
    const int*   nodes      = (const int*)d_in[0];
    const int*   neigh_idx  = (const int*)d_in[1];
    const float* node_emb   = (const float*)d_in[2];
    const float* node_prof  = (const float*)d_in[3];
    const float* neigh_emb  = (const float*)d_in[4];
    const float* neigh_prof = (const float*)d_in[5];
    const float* W_f = (const float*)d_in[6];  const float* b_f = (const float*)d_in[7];
    const float* Wa1 = (const float*)d_in[8];  const float* ba1 = (const float*)d_in[9];
    const float* Wa2 = (const float*)d_in[10]; const float* ba2 = (const float*)d_in[11];
    const float* Wa3 = (const float*)d_in[12]; const float* ba3 = (const float*)d_in[13];
    const float* W1  = (const float*)d_in[14]; const float* b1  = (const float*)d_in[15];
    const float* W2  = (const float*)d_in[16]; const float* b2  = (const float*)d_in[17];
    const float* Wc  = (const float*)d_in[18]; const float* bc  = (const float*)d_in[19];
    const float* Wt  = (const float*)d_in[20];

    float* out     = (float*)d_out;
    float* att_out = out + (size_t)B_ * E_;

    char* ws = (char*)d_ws;
    __bf16* nodes_fusion = (__bf16*)(ws);                   // 1 MB
    __bf16* node_pre     = (__bf16*)(ws + (1u << 20));      // 1 MB
    __bf16* aggB         = (__bf16*)(ws + (2u << 20));      // 3 MB
    __bf16* type_agg     = (__bf16*)(ws + (5u << 20));      // 3 MB
    __bf16* WtF          = (__bf16*)(ws + (8u << 20));      // 64 KB
    __bf16* Wa1t         = (__bf16*)(ws + (8u << 20) + 65536);
    __bf16* Wa2t         = (__bf16*)(ws + (8u << 20) + 98304);
    __bf16* W1t          = (__bf16*)(ws + (8u << 20) + 131072);

    k_prep<<<dim3(128, 4), 256, 0, stream>>>(W_f, Wa1, Wa2, W1, WtF, Wa1t, Wa2t, W1t);
    k_node_fusion<<<B_, 128, 0, stream>>>(nodes, node_emb, node_prof, W_f, b_f,
                                          nodes_fusion);
    k_node_pre<<<B_, 128, 0, stream>>>(nodes_fusion, Wa1, ba1, node_pre);
    k_neigh_att<<<dim3(B_, T_), 256, 0, stream>>>(neigh_idx, neigh_emb, neigh_prof,
                                                  WtF, Wa1t, Wa2t, b_f, ba2,
                                                  Wa3, ba3, node_pre, aggB);
    k_w1<<<(B_ * T_) / 64, 256, 0, stream>>>(aggB, W1t, b1, type_agg);
    k_final<<<B_, 128, 0, stream>>>(type_agg, nodes_fusion, Wt, W2, b2, Wc, bc,
                                    out, att_out);
}